// Round 7
// baseline (357.044 us; speedup 1.0000x reference)
//
#include <hip/hip_runtime.h>

// ---------------------------------------------------------------------------
// STCAOutputLayer: h = x@w (bf16 MFMA GEMM); E==0 identically (spk never set),
// out[b,t,d] = (M_t - S_t)*inv_norm[d] - bias[d],
// M_t = dm*(M_{t-1}+h_t), S_t = ds*(S_{t-1}+h_t); loss = 0.5*mean(out^2).
// Shapes: B=32 T=500 IN=2048 OUT=1024; M=B*T=16000, N=1024, K=2048.
//
// R7 (8-phase template port): gemm ~76us. Cycle audit: LDS stream 288KB/tile
// (2630cy reads + 750cy stage-writes) vs MFMA 2480cy -> LDS-bound + sync.
// R8: B is only 4MB (L2/L3-resident) -> take B OUT of LDS entirely:
//   - B frags loaded per-lane direct from global (dwordx4, quad-groups form
//     full 64B lines), double-buffered in registers (named sets, rule #20).
//   - LDS = A only: 2 bufs x 32KB; LDS/tile 160KB (1880cy) < MFMA (2480cy)
//     -> MFMA-bound for the first time.
//   - 1 barrier/tile (WAR on A dbuf needs exactly one); counted waits:
//     h1 vmcnt(4) lands B(t) keeps A(t+1) in flight; tile-end vmcnt(8)
//     lands A(t+1) keeps B(t+1) in flight. Drain only at final tile.
// R9 == R8 resubmitted: round-6 bench died at container acquisition
// ("MI355X container failed twice", no pytest output). Re-audited OOB
// (all loads/stores in-bounds), hangs (uniform barriers, monotone waits),
// VGPR (~250 < 256): no fault mechanism -> infra flake.
// ---------------------------------------------------------------------------

typedef __bf16 bf16x8 __attribute__((ext_vector_type(8)));
typedef __bf16 bf16x4 __attribute__((ext_vector_type(4)));
typedef float  f32x4  __attribute__((ext_vector_type(4)));

#define BDIM 32
#define TDIM 500
#define INDIM 2048
#define OUTDIM 1024
#define MROWS 16000            // B*T
#define NCHUNK 25              // scan chunks
#define CHLEN 20               // 25*20 = 500
#define OUT_ELEMS 16384000     // B*T*OUT

// ---- global -> LDS async copy, 16B per lane, LDS dest = base + lane*16 ----
__device__ __forceinline__ void gld_lds16(const void* g, void* l) {
    __builtin_amdgcn_global_load_lds(
        (const __attribute__((address_space(1))) unsigned int*)g,
        (__attribute__((address_space(3))) unsigned int*)l, 16, 0, 0);
}

// ---------------------------------------------------------------------------
// fp32 -> bf16 convert of x (pure elementwise). 8 elems / thread.
__global__ void convert_x(const float* __restrict__ x, __bf16* __restrict__ xb) {
    size_t i = ((size_t)blockIdx.x * 256 + threadIdx.x) * 8;
    float4 a = *(const float4*)(x + i);
    float4 b = *(const float4*)(x + i + 4);
    bf16x8 o;
    o[0] = (__bf16)a.x; o[1] = (__bf16)a.y; o[2] = (__bf16)a.z; o[3] = (__bf16)a.w;
    o[4] = (__bf16)b.x; o[5] = (__bf16)b.y; o[6] = (__bf16)b.z; o[7] = (__bf16)b.w;
    *(bf16x8*)(xb + i) = o;
}

// ---------------------------------------------------------------------------
// w [K=2048][N=1024] fp32 -> wbt [N][K] bf16, with fused norm[d]=sum_c w^2
__global__ void transpose_w(const float* __restrict__ w, __bf16* __restrict__ wbt,
                            float* __restrict__ normAcc) {
    __shared__ float tile[32][33];
    __shared__ float red[8][33];
    const int tx = threadIdx.x;        // 0..31
    const int ty = threadIdx.y;        // 0..7
    const int d0 = blockIdx.x * 32;    // N tile
    const int c0 = blockIdx.y * 32;    // K tile
    float s = 0.f;
#pragma unroll
    for (int i = 0; i < 4; ++i) {
        int c = c0 + ty + i * 8;
        float v = w[(size_t)c * OUTDIM + d0 + tx];
        tile[ty + i * 8][tx] = v;
        s += v * v;
    }
    red[ty][tx] = s;
    __syncthreads();
#pragma unroll
    for (int i = 0; i < 4; ++i) {
        int d = d0 + ty + i * 8;
        wbt[(size_t)d * INDIM + c0 + tx] = (__bf16)tile[tx][ty + i * 8];
    }
    if (ty == 0) {
        float t = red[0][tx] + red[1][tx] + red[2][tx] + red[3][tx]
                + red[4][tx] + red[5][tx] + red[6][tx] + red[7][tx];
        atomicAdd(&normAcc[d0 + tx], t);
    }
}

// ---------------------------------------------------------------------------
// GEMM: H[m][n] = sum_k A[m][k]*Bt[n][k], bf16 in/out (fp32 acc).
// BM=BN=256, BK=64, 8 waves (wm=wave>>2 row band, wn=wave&3 col band),
// wave tile 128x64 (2 hm-halves x 4x(2 hn x 2 j) frags of 16x16x32).
// LDS: A only, SA[2buf][half][kk][128*32] = 64KB, XOR-4 seg swizzle
// (0 conflicts measured R3-R7). B: direct global->reg, dbuf bU/bL.
// Per tile t (cur=t&1):
//   RD_A(cur,0) [8 ds]; STG_A(!cur, t+1) [4 gld_lds]; vmcnt(4) {lands B(t),
//   leaves A(t+1)}; MM(0,0)+MM(0,1) [32 MFMA on bU];
//   RD_A(cur,1) [8 ds]; BLD(bL, t+1) [8 global]; MM(1,0)+MM(1,1);
//   vmcnt(8) {lands A(t+1), leaves B(t+1)}; s_barrier.
// WAR proof (1 barrier): STG_A(t+1) targets buf !cur, last ds-read by tile
// t-1; every wave's t-1 reads complete before its MFMAs (lgkm) which
// precede its barrier -> stage issued after barrier is safe block-wide.
// vmcnt ledger queue (oldest->new) at h1 wait: [B(t)x8, A(t+1)x4] -> 4;
// at tile end: [A(t+1)x4, B(t+1)x8] -> 8. Tail t=NT-1: vmcnt(0) at h1
// (final drain), no end wait/barrier.
__global__ __launch_bounds__(512, 2) void gemm_bf16(
    const __bf16* __restrict__ A,   // [16000][2048]  (xb, lives in d_out)
    const __bf16* __restrict__ Bt,  // [1024][2048]
    __bf16* __restrict__ H)         // [16000][1024]
{
    constexpr int K  = INDIM;
    constexpr int NT = K / 64;                         // 32 K-tiles
    __shared__ __align__(16) __bf16 SA[2][2][2][4096]; // 64 KB (A only)

    const int tid  = threadIdx.x;
    const int wave = tid >> 6;          // 0..7
    const int lane = tid & 63;
    const int wm   = wave >> 2;         // 0..1
    const int wn   = wave & 3;          // 0..3

    // bijective XCD swizzle over 252 blocks (252 = 8*31+4, m204 formula)
    const int orig = blockIdx.x;
    const int xcd = orig & 7, within = orig >> 3;
    const int wgid = (xcd < 4) ? (xcd * 32 + within)
                               : (128 + (xcd - 4) * 31 + within);
    const int bm = (wgid >> 2) * 256;   // 0..15872 (last block: 128 valid rows)
    const int bn = (wgid & 3) * 256;

    // A staging lane mapping (one gld instr = 16 rows x 64B)
    const int srow = lane >> 2;
    const int sseg = lane & 3;
    const int scol = (sseg ^ ((srow >> 1) & 3)) * 8;   // pre-swizzled col (elems)
    int ra0 = bm +       wave * 16 + srow; if (ra0 > MROWS - 1) ra0 = MROWS - 1;
    int ra1 = bm + 128 + wave * 16 + srow; if (ra1 > MROWS - 1) ra1 = MROWS - 1;
    const __bf16* pA0 = A + (size_t)ra0 * K + scol;
    const __bf16* pA1 = A + (size_t)ra1 * K + scol;
    const int sdst = wave * 512;                       // elems

    // fragment mapping
    const int mrow = lane & 15, quad = lane >> 4;
    const int swzq = quad ^ ((mrow >> 1) & 3);
    const int rdA = (wm * 64 + mrow) * 32 + swzq * 8;

    // B direct-load pointers: row = bn + hn*128 + wn*32 + j*16 + mrow
    const __bf16* pB[2][2];
#pragma unroll
    for (int hn = 0; hn < 2; ++hn)
#pragma unroll
        for (int j = 0; j < 2; ++j)
            pB[hn][j] = Bt + (size_t)(bn + hn * 128 + wn * 32 + j * 16 + mrow) * K
                           + quad * 8;

    f32x4 acc[8][4] = {};
    bf16x8 a[4][2];
    bf16x8 bU[2][2][2], bL[2][2][2];   // [hn][j][kk], double-buffered

#define STG_A(NB, T1) do {                                                     \
        gld_lds16(pA0 + (size_t)(T1) * 64,      &SA[NB][0][0][sdst]);          \
        gld_lds16(pA0 + (size_t)(T1) * 64 + 32, &SA[NB][0][1][sdst]);          \
        gld_lds16(pA1 + (size_t)(T1) * 64,      &SA[NB][1][0][sdst]);          \
        gld_lds16(pA1 + (size_t)(T1) * 64 + 32, &SA[NB][1][1][sdst]); } while (0)
#define RD_A(BUF, HH) do { _Pragma("unroll")                                   \
        for (int i = 0; i < 4; ++i) {                                          \
            a[i][0] = *(const bf16x8*)&SA[BUF][HH][0][rdA + i * 512];          \
            a[i][1] = *(const bf16x8*)&SA[BUF][HH][1][rdA + i * 512]; } } while (0)
#define BLD(SET, T1) do { _Pragma("unroll")                                    \
        for (int hn = 0; hn < 2; ++hn) _Pragma("unroll")                       \
        for (int j = 0; j < 2; ++j) {                                          \
            const __bf16* p_ = pB[hn][j] + (size_t)(T1) * 64;                  \
            SET[hn][j][0] = *(const bf16x8*)(p_);                              \
            SET[hn][j][1] = *(const bf16x8*)(p_ + 32); } } while (0)
#define MM(HM, HN, SET) do { __builtin_amdgcn_s_setprio(1);                    \
        _Pragma("unroll")                                                      \
        for (int i = 0; i < 4; ++i) _Pragma("unroll")                          \
        for (int j = 0; j < 2; ++j) {                                          \
            acc[(HM)*4+i][(HN)*2+j] = __builtin_amdgcn_mfma_f32_16x16x32_bf16( \
                a[i][0], SET[HN][j][0], acc[(HM)*4+i][(HN)*2+j], 0, 0, 0);     \
            acc[(HM)*4+i][(HN)*2+j] = __builtin_amdgcn_mfma_f32_16x16x32_bf16( \
                a[i][1], SET[HN][j][1], acc[(HM)*4+i][(HN)*2+j], 0, 0, 0); }   \
        __builtin_amdgcn_s_setprio(0); } while (0)

#define TILE(T, CUR, BU, BL) do {                                              \
        const bool st_ = (T) + 1 < NT;                                         \
        RD_A(CUR, 0);                                                          \
        if (st_) STG_A(1 - (CUR), (T) + 1);                                    \
        if (st_) asm volatile("s_waitcnt vmcnt(4)" ::: "memory");              \
        else     asm volatile("s_waitcnt vmcnt(0)" ::: "memory");              \
        MM(0, 0, BU); MM(0, 1, BU);                                            \
        RD_A(CUR, 1);                                                          \
        if (st_) BLD(BL, (T) + 1);                                             \
        MM(1, 0, BU); MM(1, 1, BU);                                            \
        if (st_) {                                                             \
            asm volatile("s_waitcnt vmcnt(8)" ::: "memory");                   \
            asm volatile("s_barrier" ::: "memory");                            \
        }                                                                      \
    } while (0)

    // prologue: A(0) staged, B(0) in flight; land A(0) only (B lands at h1's
    // vmcnt(4) inside tile 0 -> never a full drain until the final tile).
    STG_A(0, 0);
    BLD(bU, 0);
    asm volatile("s_waitcnt vmcnt(8)" ::: "memory");
    asm volatile("s_barrier" ::: "memory");

#pragma unroll 1
    for (int tt = 0; tt < NT; tt += 2) {
        TILE(tt,     0, bU, bL);
        TILE(tt + 1, 1, bL, bU);
    }
#undef TILE
#undef MM
#undef BLD
#undef RD_A
#undef STG_A

    // epilogue: D[row=quad*4+r][col=mrow] per frag (m89-verified layout)
#pragma unroll
    for (int hm = 0; hm < 2; ++hm)
#pragma unroll
        for (int i = 0; i < 4; ++i)
#pragma unroll
            for (int hn = 0; hn < 2; ++hn)
#pragma unroll
                for (int j = 0; j < 2; ++j)
#pragma unroll
                    for (int r = 0; r < 4; ++r) {
                        const int R = bm + hm * 128 + wm * 64 + i * 16 + quad * 4 + r;
                        const int C = bn + hn * 128 + wn * 32 + j * 16 + mrow;
                        if (R < MROWS)
                            H[(size_t)R * OUTDIM + C] = (__bf16)acc[hm * 4 + i][hn * 2 + j][r];
                    }
}

// ---------------------------------------------------------------------------
// scan pass 1: per (chunk c, batch b): local M/S with zero carry-in; store
// chunk-end values.  256 threads cover all 1024 d (float4 each).
__global__ void scan1(const __bf16* __restrict__ H,
                      f32x4* __restrict__ cM, f32x4* __restrict__ cS,
                      const float* __restrict__ dmp, const float* __restrict__ dsp) {
    const float dm = *dmp, ds = *dsp;
    const int c = blockIdx.x, b = blockIdx.y, tid = threadIdx.x;
    f32x4 M = {}, S = {};
    const __bf16* p = H + ((size_t)b * TDIM + c * CHLEN) * OUTDIM + tid * 4;
#pragma unroll 4
    for (int t = 0; t < CHLEN; ++t) {
        bf16x4 hv = *(const bf16x4*)(p + (size_t)t * OUTDIM);
        f32x4 h; h[0] = hv[0]; h[1] = hv[1]; h[2] = hv[2]; h[3] = hv[3];
        M = dm * (M + h);
        S = ds * (S + h);
    }
    const size_t idx = ((size_t)c * BDIM + b) * 256 + tid;
    cM[idx] = M;
    cS[idx] = S;
}

// ---------------------------------------------------------------------------
// scan pass 2: chunk-end values -> per-chunk carry-INs (in place).
__global__ void scan2(float* __restrict__ cM, float* __restrict__ cS,
                      const float* __restrict__ dmp, const float* __restrict__ dsp) {
    const float dm = *dmp, ds = *dsp;
    float km = 1.f, ks = 1.f;
#pragma unroll
    for (int i = 0; i < CHLEN; ++i) { km *= dm; ks *= ds; }
    const int gid = blockIdx.x * 256 + threadIdx.x;   // 0..32767
    const int b = gid >> 10, d = gid & 1023;
    float tM = 0.f, tS = 0.f;
    for (int c = 0; c < NCHUNK; ++c) {
        const size_t idx = (((size_t)c * BDIM + b) << 10) + d;
        float oM = cM[idx], oS = cS[idx];
        cM[idx] = tM; cS[idx] = tS;
        tM = km * tM + oM;
        tS = ks * tS + oS;
    }
}

// ---------------------------------------------------------------------------
// scan pass 3: recompute with carry-in, write out, accumulate loss; last
// block (device-scope ticket) writes the final loss scalar.
__global__ void scan3(const __bf16* __restrict__ H,
                      const f32x4* __restrict__ cM, const f32x4* __restrict__ cS,
                      const float* __restrict__ normAcc, const float* __restrict__ bias,
                      const float* __restrict__ dmp, const float* __restrict__ dsp,
                      float* __restrict__ out, float* __restrict__ lossAcc,
                      unsigned* __restrict__ ticket) {
    const float dm = *dmp, ds = *dsp;
    const int c = blockIdx.x, b = blockIdx.y, tid = threadIdx.x;
    const size_t cidx = ((size_t)c * BDIM + b) * 256 + tid;
    f32x4 M = cM[cidx];
    f32x4 S = cS[cidx];
    f32x4 nv = *(const f32x4*)(normAcc + tid * 4);
    f32x4 inv;
    inv[0] = 1.f / (nv[0] + 1e-8f); inv[1] = 1.f / (nv[1] + 1e-8f);
    inv[2] = 1.f / (nv[2] + 1e-8f); inv[3] = 1.f / (nv[3] + 1e-8f);
    f32x4 bv = *(const f32x4*)(bias + tid * 4);

    const size_t rowbase = ((size_t)b * TDIM + c * CHLEN) * OUTDIM + tid * 4;
    const __bf16* p = H + rowbase;
    float* o = out + rowbase;
    float loss = 0.f;
#pragma unroll 4
    for (int t = 0; t < CHLEN; ++t) {
        bf16x4 hv = *(const bf16x4*)(p + (size_t)t * OUTDIM);
        f32x4 h; h[0] = hv[0]; h[1] = hv[1]; h[2] = hv[2]; h[3] = hv[3];
        M = dm * (M + h);
        S = ds * (S + h);
        f32x4 r = (M - S) * inv - bv;
        *(f32x4*)(o + (size_t)t * OUTDIM) = r;
        loss += r[0] * r[0] + r[1] * r[1] + r[2] * r[2] + r[3] * r[3];
    }
    __shared__ float red[256];
    red[tid] = loss;
    __syncthreads();
    for (int s = 128; s > 0; s >>= 1) {
        if (tid < s) red[tid] += red[tid + s];
        __syncthreads();
    }
    if (tid == 0) {
        atomicAdd(lossAcc, red[0]);
        __threadfence();
        unsigned t = atomicAdd(ticket, 1u);
        if (t == NCHUNK * BDIM - 1) {
            float total = atomicAdd(lossAcc, 0.0f);   // coherent read
            out[OUT_ELEMS] = 0.5f * total / (float)OUT_ELEMS;
        }
    }
}

// ---------------------------------------------------------------------------
// Workspace layout (bytes):
//   H      (bf16 16000x1024) : 0          .. 32,768,000
//   WBT    (bf16 1024x2048)  : 32,768,000 .. 36,962,304
//   NORM   (f32 1024)        : 36,962,304 .. +4096
//   LOSS   (f32 1)           : 36,966,400
//   TICKET (u32 1)           : 36,966,404
//   CM     (f32 25*32*1024)  : 36,966,656 .. +3,276,800
//   CS                       : 40,243,456 .. +3,276,800   (end 43,520,256)
// xb (bf16 x) lives in d_out (exactly 65,536,000 B) until scan3 overwrites it.
#define OFF_H      ((size_t)0)
#define OFF_WBT    ((size_t)32768000)
#define OFF_NORM   ((size_t)36962304)
#define OFF_LOSS   ((size_t)36966400)
#define OFF_TICKET ((size_t)36966404)
#define OFF_CM     ((size_t)36966656)
#define OFF_CS     ((size_t)40243456)

extern "C" void kernel_launch(void* const* d_in, const int* in_sizes, int n_in,
                              void* d_out, int out_size, void* d_ws, size_t ws_size,
                              hipStream_t stream) {
    const float* x  = (const float*)d_in[0];
    const float* w  = (const float*)d_in[1];
    const float* bb = (const float*)d_in[2];
    const float* dm = (const float*)d_in[3];
    const float* ds = (const float*)d_in[4];

    char* ws = (char*)d_ws;
    __bf16*   H    = (__bf16*)(ws + OFF_H);
    __bf16*   WBT  = (__bf16*)(ws + OFF_WBT);
    float*    NORM = (float*)(ws + OFF_NORM);
    float*    LOSS = (float*)(ws + OFF_LOSS);
    unsigned* TICK = (unsigned*)(ws + OFF_TICKET);
    f32x4*    CM   = (f32x4*)(ws + OFF_CM);
    f32x4*    CS   = (f32x4*)(ws + OFF_CS);
    __bf16*   XB   = (__bf16*)d_out;          // scratch: bf16 x (exact fit)
    float*    out  = (float*)d_out;

    hipMemsetAsync(ws + OFF_NORM, 0, 4096 + 256, stream);   // NORM+LOSS+TICKET

    convert_x<<<16000, 256, 0, stream>>>(x, XB);
    transpose_w<<<dim3(32, 64), dim3(32, 8), 0, stream>>>(w, WBT, NORM);
    gemm_bf16<<<252, 512, 0, stream>>>(XB, WBT, H);
    scan1<<<dim3(NCHUNK, BDIM), 256, 0, stream>>>(H, CM, CS, dm, ds);
    scan2<<<128, 256, 0, stream>>>((float*)CM, (float*)CS, dm, ds);
    scan3<<<dim3(NCHUNK, BDIM), 256, 0, stream>>>(H, CM, CS, NORM, bb, dm, ds,
                                                  out, LOSS, TICK);
}